// Round 10
// baseline (286.539 us; speedup 1.0000x reference)
//
#include <hip/hip_runtime.h>
#include <hip/hip_bf16.h>
#include <stdint.h>

typedef __bf16 bf;
typedef __bf16 v8bf __attribute__((ext_vector_type(8)));
typedef float v4f __attribute__((ext_vector_type(4)));

#define SEQ   197
#define HEADS 12
#define HID   768
#define NQKV  2304
#define MTOT  12608   // 64*197
#define SVS   210     // sV row stride: 420B = 105 banks == 9 mod 32 (odd -> bijective, conflict-free)

__device__ __forceinline__ void gload_lds16(const void* g, void* l) {
    __builtin_amdgcn_global_load_lds(
        (const __attribute__((address_space(1))) void*)g,
        (__attribute__((address_space(3))) void*)l, 16, 0, 0);
}

// ---------------- kernel 0: X fp32 -> bf16, float4-vectorized ---------------
__global__ void kx(const float* __restrict__ x, bf* __restrict__ xb) {
    int idx = blockIdx.x * 256 + threadIdx.x;      // over float4: 9682944/4 = 2420736
    float4 v = ((const float4*)x)[idx];
    bf o[4] = {(bf)v.x, (bf)v.y, (bf)v.z, (bf)v.w};
    ((uint2*)xb)[idx] = *(uint2*)o;
}

// ---------------- kernel 1: weights -> Wt[2304][768] via LDS tile transpose -
__global__ void kwt(const float* __restrict__ wq, const float* __restrict__ wk,
                    const float* __restrict__ wv, bf* __restrict__ wt) {
    __shared__ float t[64][65];
    const float* W = (blockIdx.z == 0) ? wq : (blockIdx.z == 1 ? wk : wv);
    int kt = blockIdx.x * 64, nt = blockIdx.y * 64;
    int r  = threadIdx.x >> 4;            // 0..15
    int c4 = (threadIdx.x & 15) * 4;      // 0..60
#pragma unroll
    for (int p = 0; p < 64; p += 16) {
        float4 v = *(const float4*)(W + (size_t)(kt + p + r) * 768 + nt + c4);
        t[p + r][c4 + 0] = v.x; t[p + r][c4 + 1] = v.y;
        t[p + r][c4 + 2] = v.z; t[p + r][c4 + 3] = v.w;
    }
    __syncthreads();
#pragma unroll
    for (int p = 0; p < 64; p += 16) {
        int i = p + r;                    // n within tile
        bf o[4];
#pragma unroll
        for (int j = 0; j < 4; j++) o[j] = (bf)t[c4 + j][i];   // Wt[n][k] = W[k][n]
        *(uint2*)(wt + (size_t)(blockIdx.z * 768 + nt + i) * 768 + kt + c4) = *(uint2*)o;
    }
}

// ---------------- kernel 2: bias[12][208][208] fp32 -------------------------
__global__ void kbias(const float* __restrict__ table, float* __restrict__ bias) {
    int idx = blockIdx.x * 256 + threadIdx.x;      // 12*208*208 = 519168 exact
    int h = idx / (208 * 208);
    int r = idx % (208 * 208);
    int i = r / 208, j = r % 208;
    float v = 0.f;
    if (i < SEQ && j < SEQ) {
        int rpi;
        if (i == 0 && j == 0)      rpi = 731;
        else if (i == 0)           rpi = 729;
        else if (j == 0)           rpi = 730;
        else {
            int hp = (i - 1) / 14, wp = (i - 1) % 14;
            int hq = (j - 1) / 14, wq = (j - 1) % 14;
            rpi = (hp - hq + 13) * 27 + (wp - wq + 13);
        }
        v = table[rpi * 12 + h];
    }
    bias[idx] = v;
}

// ---------------- kernel 3: fused QKV GEMM, XOR-swizzled LDS, 4 blk/CU ------
__launch_bounds__(256, 4)
__global__ void kgemm(const bf* __restrict__ X, const bf* __restrict__ Wt,
                      const float* __restrict__ bq, const float* __restrict__ bv,
                      bf* __restrict__ C) {
    __shared__ __align__(16) bf smA[128 * 64];
    __shared__ __align__(16) bf smB[128 * 64];
    const int tid  = threadIdx.x;
    const int wave = tid >> 6, lane = tid & 63;
    const int quad = lane >> 4, l16 = lane & 15;
    const int m0 = blockIdx.x * 128;     // gridDim.x = 99 (last tile partial)
    const int n0 = blockIdx.y * 128;     // gridDim.y = 18
    const int wm = (wave >> 1) * 64, wn = (wave & 1) * 64;
    const int sw = l16 & 7;              // reader-side XOR swizzle key

    v4f acc[4][4];
#pragma unroll
    for (int i = 0; i < 4; i++)
#pragma unroll
        for (int j = 0; j < 4; j++) acc[i][j] = (v4f){0.f, 0.f, 0.f, 0.f};

    for (int k0 = 0; k0 < HID; k0 += 64) {
#pragma unroll
        for (int c = 0; c < 4; c++) {
            int chunkbase = c * 256 + wave * 64;       // wave-uniform
            int chunk = chunkbase + lane;
            int row = chunk >> 3;
            int col = ((chunk ^ row) & 7) << 3;        // XOR bank swizzle
            int arow = m0 + row; if (arow > MTOT - 1) arow = MTOT - 1;
            gload_lds16(X  + (size_t)arow * HID + k0 + col, smA + chunkbase * 8);
            gload_lds16(Wt + (size_t)(n0 + row) * HID + k0 + col, smB + chunkbase * 8);
        }
        __syncthreads();
#pragma unroll
        for (int ks = 0; ks < 2; ks++) {
            v8bf afr[4], bfr[4];
#pragma unroll
            for (int i = 0; i < 4; i++)
                afr[i] = *(const v8bf*)(smA + (wm + i * 16 + l16) * 64
                                        + (((ks * 4 + quad) ^ sw) << 3));
#pragma unroll
            for (int j = 0; j < 4; j++)
                bfr[j] = *(const v8bf*)(smB + (wn + j * 16 + l16) * 64
                                        + (((ks * 4 + quad) ^ sw) << 3));
#pragma unroll
            for (int i = 0; i < 4; i++)
#pragma unroll
                for (int j = 0; j < 4; j++)
                    acc[i][j] = __builtin_amdgcn_mfma_f32_16x16x32_bf16(
                        afr[i], bfr[j], acc[i][j], 0, 0, 0);
        }
        __syncthreads();
    }

#pragma unroll
    for (int i = 0; i < 4; i++) {
        int mbase = m0 + wm + i * 16 + quad * 4;
#pragma unroll
        for (int j = 0; j < 4; j++) {
            int n = n0 + wn + j * 16 + l16;
#pragma unroll
            for (int r = 0; r < 4; r++) {
                int m = mbase + r;
                if (m < MTOT) {
                    float v = acc[i][j][r];
                    if (n < 768)        v = (v + bq[n]) * 0.125f;   // Q: +bq, *1/sqrt(64)
                    else if (n >= 1536) v = v + bv[n - 1536];       // V: +bv
                    C[(size_t)m * NQKV + n] = (bf)v;
                }
            }
        }
    }
}

// ---------------- kernel 4: attention, S^T + shuffle-PV, 3 blocks/CU --------
// LDS = sK 26624 (XOR-swizzled) + sV 26880 (stride 210) = 53504 B -> 3 blk/CU,
// grid 768 fully co-resident. P never touches LDS: PV A-frags rebuilt with
// cross-quad shuffles from the S^T C-layout registers.
__launch_bounds__(256, 3)
__global__ void kattn(const bf* __restrict__ C, const float* __restrict__ bias,
                      float* __restrict__ out) {
    __shared__ __align__(16) bf sK[208 * 64];      // 26624 B, XOR-swizzled chunks
    __shared__ __align__(16) bf sV[64 * SVS];      // 26880 B, conflict-free stride
    const int tid  = threadIdx.x;
    const int wave = tid >> 6, lane = tid & 63;
    const int quad = lane >> 4, l16 = lane & 15;
    const int b = blockIdx.x / HEADS, h = blockIdx.x % HEADS;
    const bf* Cb = C + (size_t)b * SEQ * NQKV;

    // stage K [208][64], logical chunk c8 of row s at physical chunk c8^(s&7)
    for (int chunk = tid; chunk < 208 * 8; chunk += 256) {
        int s = chunk >> 3, c8 = chunk & 7;
        int cphys = (c8 ^ (s & 7)) << 3;
        if (s < SEQ)
            *(uint4*)(sK + s * 64 + cphys) =
                *(const uint4*)(Cb + (size_t)s * NQKV + 768 + h * 64 + (c8 << 3));
        else
            *(uint4*)(sK + s * 64 + cphys) = make_uint4(0, 0, 0, 0);
    }
    // stage V transposed, s-major lanes (consecutive lanes -> consecutive banks)
#pragma unroll
    for (int it = 0; it < 8; it++) {
        int s = tid, c = it * 8;
        if (s < SEQ) {
            uint4 raw = *(const uint4*)(Cb + (size_t)s * NQKV + 1536 + h * 64 + c);
            bf tmp[8]; *(uint4*)tmp = raw;
#pragma unroll
            for (int t = 0; t < 8; t++) sV[(c + t) * SVS + s] = tmp[t];
        }
    }
    // zero V pad cols 197..209
    for (int idx = tid; idx < 64 * 13; idx += 256) {
        int d = idx / 13, s = SEQ + idx % 13;
        sV[d * SVS + s] = (bf)0.f;
    }
    __syncthreads();

    const float* biash = bias + (size_t)h * 208 * 208;
    const int swk = l16 & 7;                       // sK reader swizzle key
    const int src_lo = (quad & 1) * 32 + l16;      // source lane qc*16+l16, qc=2*(quad&1)
    const int src_hi = src_lo + 16;                // qc+1
    const bool ntsel = (quad >> 1) != 0;           // pk[2ks] vs pk[2ks+1]

    for (int st = wave; st < 13; st += 4) {
        int s0 = st * 16;
        // Q as B-operand: lane l16 = query row i (clamped; rows>=197 never stored)
        int qrow = s0 + l16; if (qrow > SEQ - 1) qrow = SEQ - 1;
        v8bf bQ[2];
#pragma unroll
        for (int ks = 0; ks < 2; ks++)
            bQ[ks] = *(const v8bf*)(Cb + (size_t)qrow * NQKV + h * 64 + ks * 32 + quad * 8);

        // S^T tiles: sc[nt][r] = S^T[j = nt*16+quad*4+r][i = l16]
        const float* brow = biash + (size_t)(s0 + l16) * 208;
        v4f sc[13];
#pragma unroll
        for (int nt = 0; nt < 13; nt++) {
            v4f a = (v4f){0.f, 0.f, 0.f, 0.f};
#pragma unroll
            for (int ks = 0; ks < 2; ks++) {
                v8bf aK = *(const v8bf*)(sK + (nt * 16 + l16) * 64
                                         + (((ks * 4 + quad) ^ swk) << 3));
                a = __builtin_amdgcn_mfma_f32_16x16x32_bf16(aK, bQ[ks], a, 0, 0, 0);
            }
            int j0 = nt * 16 + quad * 4;
            float4 b4 = *(const float4*)(brow + j0);
            const float* b4p = (const float*)&b4;
#pragma unroll
            for (int r = 0; r < 4; r++) {
                float v = a[r] + b4p[r];
                if (j0 + r >= SEQ) v = -1e30f;
                a[r] = v;
            }
            sc[nt] = a;
        }
        // softmax over j: in-lane + 2 cross-shuffles
        float m = sc[0][0];
#pragma unroll
        for (int nt = 0; nt < 13; nt++)
#pragma unroll
            for (int r = 0; r < 4; r++) m = fmaxf(m, sc[nt][r]);
        m = fmaxf(m, __shfl_xor(m, 16));
        m = fmaxf(m, __shfl_xor(m, 32));
        float sum = 0.f;
#pragma unroll
        for (int nt = 0; nt < 13; nt++)
#pragma unroll
            for (int r = 0; r < 4; r++) {
                float e = __expf(sc[nt][r] - m);
                sc[nt][r] = e; sum += e;
            }
        sum += __shfl_xor(sum, 16);
        sum += __shfl_xor(sum, 32);
        float inv = 1.f / sum;

        // pack normalized P: pk[nt][e] = bf16 pair (p[2e], p[2e+1])
        unsigned int pk[13][2];
#pragma unroll
        for (int nt = 0; nt < 13; nt++) {
            union { bf hh[2]; unsigned int u; } u0, u1;
            u0.hh[0] = (bf)(sc[nt][0] * inv); u0.hh[1] = (bf)(sc[nt][1] * inv);
            u1.hh[0] = (bf)(sc[nt][2] * inv); u1.hh[1] = (bf)(sc[nt][3] * inv);
            pk[nt][0] = u0.u; pk[nt][1] = u1.u;
        }

        // out = P @ V; A-frag via cross-quad shuffles (no LDS round-trip)
        v4f o[4];
#pragma unroll
        for (int n2 = 0; n2 < 4; n2++) o[n2] = (v4f){0.f, 0.f, 0.f, 0.f};
#pragma unroll
        for (int ks = 0; ks < 7; ks++) {
            unsigned int w[4];
            if (ks < 6) {
                unsigned int a0 = (unsigned)__shfl((int)pk[2*ks  ][0], src_lo);
                unsigned int b0 = (unsigned)__shfl((int)pk[2*ks+1][0], src_lo);
                unsigned int a1 = (unsigned)__shfl((int)pk[2*ks  ][1], src_lo);
                unsigned int b1 = (unsigned)__shfl((int)pk[2*ks+1][1], src_lo);
                unsigned int a2 = (unsigned)__shfl((int)pk[2*ks  ][0], src_hi);
                unsigned int b2 = (unsigned)__shfl((int)pk[2*ks+1][0], src_hi);
                unsigned int a3 = (unsigned)__shfl((int)pk[2*ks  ][1], src_hi);
                unsigned int b3 = (unsigned)__shfl((int)pk[2*ks+1][1], src_hi);
                w[0] = ntsel ? b0 : a0; w[1] = ntsel ? b1 : a1;
                w[2] = ntsel ? b2 : a2; w[3] = ntsel ? b3 : a3;
            } else {
                // ks=6: nt=12 for quads 0,1; j>=208 (zero) for quads 2,3
                unsigned int a0 = (unsigned)__shfl((int)pk[12][0], src_lo);
                unsigned int a1 = (unsigned)__shfl((int)pk[12][1], src_lo);
                unsigned int a2 = (unsigned)__shfl((int)pk[12][0], src_hi);
                unsigned int a3 = (unsigned)__shfl((int)pk[12][1], src_hi);
                w[0] = ntsel ? 0u : a0; w[1] = ntsel ? 0u : a1;
                w[2] = ntsel ? 0u : a2; w[3] = ntsel ? 0u : a3;
            }
            uint4 av = make_uint4(w[0], w[1], w[2], w[3]);
            v8bf aP = *(v8bf*)&av;
            int koff = ks * 32 + quad * 8;
            if (ks == 6 && quad >= 2) koff = 0;    // aP is zero there; keep read in-bounds
#pragma unroll
            for (int n2 = 0; n2 < 4; n2++) {
                v8bf bV = *(const v8bf*)(sV + (n2 * 16 + l16) * SVS + koff);
                o[n2] = __builtin_amdgcn_mfma_f32_16x16x32_bf16(aP, bV, o[n2], 0, 0, 0);
            }
        }
        // store: row s = s0+quad*4+r, col d = n2*16+l16 (coalesced 64B)
#pragma unroll
        for (int r = 0; r < 4; r++) {
            int s = s0 + quad * 4 + r;
            if (s < SEQ) {
#pragma unroll
                for (int n2 = 0; n2 < 4; n2++) {
                    int d = n2 * 16 + l16;
                    out[((size_t)b * SEQ + s) * HID + h * 64 + d] = o[n2][r];
                }
            }
        }
    }
}

// ---------------- launcher (exact round-3 workspace map) --------------------
extern "C" void kernel_launch(void* const* d_in, const int* in_sizes, int n_in,
                              void* d_out, int out_size, void* d_ws, size_t ws_size,
                              hipStream_t stream) {
    const float* X   = (const float*)d_in[0];
    const float* wq  = (const float*)d_in[1];
    const float* bq  = (const float*)d_in[2];
    const float* wk  = (const float*)d_in[3];
    const float* wv  = (const float*)d_in[4];
    const float* bv  = (const float*)d_in[5];
    const float* tbl = (const float*)d_in[6];
    float* out = (float*)d_out;

    char* ws = (char*)d_ws;
    bf*    Xb   = (bf*)ws;                          // 12608*768*2  = 19,365,888 B
    bf*    Wt   = (bf*)(ws + 19365888);             // 2304*768*2   =  3,538,944 B
    bf*    C    = (bf*)(ws + 22904832);             // 12608*2304*2 = 58,097,664 B
    float* bias = (float*)(ws + 81002496);          // 12*208*208*4 =  2,076,672 B

    kx   <<<9456, 256, 0, stream>>>(X, Xb);
    kwt  <<<dim3(12, 12, 3), 256, 0, stream>>>(wq, wk, wv, Wt);
    kbias<<<2028, 256, 0, stream>>>(tbl, bias);
    dim3 g(99, 18);
    kgemm<<<g, 256, 0, stream>>>(Xb, Wt, bq, bv, C);
    kattn<<<768, 256, 0, stream>>>(C, bias, out);
}

// Round 11
// 257.081 us; speedup vs baseline: 1.1146x; 1.1146x over previous
//
#include <hip/hip_runtime.h>
#include <hip/hip_bf16.h>
#include <stdint.h>

typedef __bf16 bf;
typedef __bf16 v8bf __attribute__((ext_vector_type(8)));
typedef float v4f __attribute__((ext_vector_type(4)));

#define SEQ   197
#define HEADS 12
#define HID   768
#define NQKV  2304
#define MTOT  12608   // 64*197
#define SVS   210     // sV row stride: conflict-free-ish reads (bank step 9 odd)
#define SPS   216     // sP row stride: 2-way reads

__device__ __forceinline__ void gload_lds16(const void* g, void* l) {
    __builtin_amdgcn_global_load_lds(
        (const __attribute__((address_space(1))) void*)g,
        (__attribute__((address_space(3))) void*)l, 16, 0, 0);
}

// ---------------- kernel 0: fused preprocessing -----------------------------
// blocks [0,9456): X fp32->bf16 (float4); [9456,9888): weight transpose tiles;
// [9888,11916): bias table expansion. Disjoint outputs, block-uniform branch.
__global__ void kprep(const float* __restrict__ X, const float* __restrict__ wq,
                      const float* __restrict__ wk, const float* __restrict__ wv,
                      const float* __restrict__ tbl,
                      bf* __restrict__ xb, bf* __restrict__ wt, float* __restrict__ bias) {
    __shared__ float t[64][65];
    const int blk = blockIdx.x;
    if (blk < 9456) {                       // ---- kx: 2420736 float4 chunks
        int idx = blk * 256 + threadIdx.x;
        float4 v = ((const float4*)X)[idx];
        bf o[4] = {(bf)v.x, (bf)v.y, (bf)v.z, (bf)v.w};
        ((uint2*)xb)[idx] = *(uint2*)o;
    } else if (blk < 9888) {                // ---- kwt: 432 tiles (12,12,3)
        int tt = blk - 9456;
        int bz = tt / 144, rr = tt % 144;
        int bx = rr / 12, by = rr % 12;
        const float* W = (bz == 0) ? wq : (bz == 1 ? wk : wv);
        int kt = bx * 64, nt = by * 64;
        int r  = threadIdx.x >> 4;          // 0..15
        int c4 = (threadIdx.x & 15) * 4;    // 0..60
#pragma unroll
        for (int p = 0; p < 64; p += 16) {
            float4 v = *(const float4*)(W + (size_t)(kt + p + r) * 768 + nt + c4);
            t[p + r][c4 + 0] = v.x; t[p + r][c4 + 1] = v.y;
            t[p + r][c4 + 2] = v.z; t[p + r][c4 + 3] = v.w;
        }
        __syncthreads();
#pragma unroll
        for (int p = 0; p < 64; p += 16) {
            int i = p + r;
            bf o[4];
#pragma unroll
            for (int j = 0; j < 4; j++) o[j] = (bf)t[c4 + j][i];   // Wt[n][k]=W[k][n]
            *(uint2*)(wt + (size_t)(bz * 768 + nt + i) * 768 + kt + c4) = *(uint2*)o;
        }
    } else {                                // ---- kbias: 12*208*208 elems
        int idx = (blk - 9888) * 256 + threadIdx.x;
        int h = idx / (208 * 208);
        int r = idx % (208 * 208);
        int i = r / 208, j = r % 208;
        float v = 0.f;
        if (i < SEQ && j < SEQ) {
            int rpi;
            if (i == 0 && j == 0)      rpi = 731;
            else if (i == 0)           rpi = 729;
            else if (j == 0)           rpi = 730;
            else {
                int hp = (i - 1) / 14, wp = (i - 1) % 14;
                int hq = (j - 1) / 14, wq2 = (j - 1) % 14;
                rpi = (hp - hq + 13) * 27 + (wp - wq2 + 13);
            }
            v = tbl[rpi * 12 + h];
        }
        bias[idx] = v;
    }
}

// ---------------- kernel 3: fused QKV GEMM, XOR-swizzled LDS ----------------
__launch_bounds__(256, 4)
__global__ void kgemm(const bf* __restrict__ X, const bf* __restrict__ Wt,
                      const float* __restrict__ bq, const float* __restrict__ bv,
                      bf* __restrict__ C) {
    __shared__ __align__(16) bf smA[128 * 64];
    __shared__ __align__(16) bf smB[128 * 64];
    const int tid  = threadIdx.x;
    const int wave = tid >> 6, lane = tid & 63;
    const int quad = lane >> 4, l16 = lane & 15;
    const int m0 = blockIdx.x * 128;     // gridDim.x = 99 (last tile partial)
    const int n0 = blockIdx.y * 128;     // gridDim.y = 18
    const int wm = (wave >> 1) * 64, wn = (wave & 1) * 64;
    const int sw = l16 & 7;              // reader-side XOR swizzle key

    v4f acc[4][4];
#pragma unroll
    for (int i = 0; i < 4; i++)
#pragma unroll
        for (int j = 0; j < 4; j++) acc[i][j] = (v4f){0.f, 0.f, 0.f, 0.f};

    for (int k0 = 0; k0 < HID; k0 += 64) {
#pragma unroll
        for (int c = 0; c < 4; c++) {
            int chunkbase = c * 256 + wave * 64;       // wave-uniform
            int chunk = chunkbase + lane;
            int row = chunk >> 3;
            int col = ((chunk ^ row) & 7) << 3;        // XOR bank swizzle
            int arow = m0 + row; if (arow > MTOT - 1) arow = MTOT - 1;
            gload_lds16(X  + (size_t)arow * HID + k0 + col, smA + chunkbase * 8);
            gload_lds16(Wt + (size_t)(n0 + row) * HID + k0 + col, smB + chunkbase * 8);
        }
        __syncthreads();
#pragma unroll
        for (int ks = 0; ks < 2; ks++) {
            v8bf afr[4], bfr[4];
#pragma unroll
            for (int i = 0; i < 4; i++)
                afr[i] = *(const v8bf*)(smA + (wm + i * 16 + l16) * 64
                                        + (((ks * 4 + quad) ^ sw) << 3));
#pragma unroll
            for (int j = 0; j < 4; j++)
                bfr[j] = *(const v8bf*)(smB + (wn + j * 16 + l16) * 64
                                        + (((ks * 4 + quad) ^ sw) << 3));
#pragma unroll
            for (int i = 0; i < 4; i++)
#pragma unroll
                for (int j = 0; j < 4; j++)
                    acc[i][j] = __builtin_amdgcn_mfma_f32_16x16x32_bf16(
                        afr[i], bfr[j], acc[i][j], 0, 0, 0);
        }
        __syncthreads();
    }

#pragma unroll
    for (int i = 0; i < 4; i++) {
        int mbase = m0 + wm + i * 16 + quad * 4;
#pragma unroll
        for (int j = 0; j < 4; j++) {
            int n = n0 + wn + j * 16 + l16;
#pragma unroll
            for (int r = 0; r < 4; r++) {
                int m = mbase + r;
                if (m < MTOT) {
                    float v = acc[i][j][r];
                    if (n < 768)        v = (v + bq[n]) * 0.125f;   // Q: +bq, *1/sqrt(64)
                    else if (n >= 1536) v = v + bv[n - 1536];       // V: +bv
                    C[(size_t)m * NQKV + n] = (bf)v;
                }
            }
        }
    }
}

// ---------------- kernel 4: attention, S^T + sP, conflict-free, 2 blk/CU ----
// LDS = sK 26624 (XOR) + sV 26880 (stride 210) + sP 27648 (stride 216)
//     = 81152 B <= 81920 -> 2 blocks/CU. All staging coalesced (chunk-based).
__launch_bounds__(256, 2)
__global__ void kattn(const bf* __restrict__ C, const float* __restrict__ bias,
                      float* __restrict__ out) {
    __shared__ __align__(16) bf sK[208 * 64];
    __shared__ __align__(16) bf sV[64 * SVS];
    __shared__ __align__(16) bf sP[4][16 * SPS];
    const int tid  = threadIdx.x;
    const int wave = tid >> 6, lane = tid & 63;
    const int quad = lane >> 4, l16 = lane & 15;
    const int b = blockIdx.x / HEADS, h = blockIdx.x % HEADS;
    const bf* Cb = C + (size_t)b * SEQ * NQKV;

    // stage K [208][64], coalesced; logical chunk c8 of row s at chunk c8^(s&7)
    for (int chunk = tid; chunk < 208 * 8; chunk += 256) {
        int s = chunk >> 3, c8 = chunk & 7;
        int cphys = (c8 ^ (s & 7)) << 3;
        if (s < SEQ)
            *(uint4*)(sK + s * 64 + cphys) =
                *(const uint4*)(Cb + (size_t)s * NQKV + 768 + h * 64 + (c8 << 3));
        else
            *(uint4*)(sK + s * 64 + cphys) = make_uint4(0, 0, 0, 0);
    }
    // stage V transposed, chunk-based COALESCED global reads (8 lanes = 128B row)
    for (int chunk = tid; chunk < SEQ * 8; chunk += 256) {
        int s = chunk >> 3, c = (chunk & 7) << 3;
        uint4 raw = *(const uint4*)(Cb + (size_t)s * NQKV + 1536 + h * 64 + c);
        bf tmp[8]; *(uint4*)tmp = raw;
#pragma unroll
        for (int t = 0; t < 8; t++) sV[(c + t) * SVS + s] = tmp[t];
    }
    // zero V pad cols 197..209
    for (int idx = tid; idx < 64 * 13; idx += 256) {
        int d = idx / 13, s = SEQ + idx % 13;
        sV[d * SVS + s] = (bf)0.f;
    }
    __syncthreads();

    const float* biash = bias + (size_t)h * 208 * 208;
    const int swk = l16 & 7;
    bf* P = sP[wave];

    for (int st = wave; st < 13; st += 4) {
        int s0 = st * 16;
        // Q as B-operand: lane l16 = query row i (clamped; rows>=197 never stored)
        int qrow = s0 + l16; if (qrow > SEQ - 1) qrow = SEQ - 1;
        v8bf bQ[2];
#pragma unroll
        for (int ks = 0; ks < 2; ks++)
            bQ[ks] = *(const v8bf*)(Cb + (size_t)qrow * NQKV + h * 64 + ks * 32 + quad * 8);

        // S^T tiles: sc[nt][r] = S^T[j=nt*16+quad*4+r][i=l16]
        const float* brow = biash + (size_t)(s0 + l16) * 208;
        v4f sc[13];
#pragma unroll
        for (int nt = 0; nt < 13; nt++) {
            v4f a = (v4f){0.f, 0.f, 0.f, 0.f};
#pragma unroll
            for (int ks = 0; ks < 2; ks++) {
                v8bf aK = *(const v8bf*)(sK + (nt * 16 + l16) * 64
                                         + (((ks * 4 + quad) ^ swk) << 3));
                a = __builtin_amdgcn_mfma_f32_16x16x32_bf16(aK, bQ[ks], a, 0, 0, 0);
            }
            int j0 = nt * 16 + quad * 4;
            float4 b4 = *(const float4*)(brow + j0);
            const float* b4p = (const float*)&b4;
#pragma unroll
            for (int r = 0; r < 4; r++) {
                float v = a[r] + b4p[r];
                if (j0 + r >= SEQ) v = -1e30f;
                a[r] = v;
            }
            sc[nt] = a;
        }
        // softmax over j: in-lane + 2 cross-shuffles
        float m = sc[0][0];
#pragma unroll
        for (int nt = 0; nt < 13; nt++)
#pragma unroll
            for (int r = 0; r < 4; r++) m = fmaxf(m, sc[nt][r]);
        m = fmaxf(m, __shfl_xor(m, 16));
        m = fmaxf(m, __shfl_xor(m, 32));
        float sum = 0.f;
#pragma unroll
        for (int nt = 0; nt < 13; nt++)
#pragma unroll
            for (int r = 0; r < 4; r++) {
                float e = __expf(sc[nt][r] - m);
                sc[nt][r] = e; sum += e;
            }
        sum += __shfl_xor(sum, 16);
        sum += __shfl_xor(sum, 32);
        float inv = 1.f / sum;

        // normalized P -> sP[i=l16][j], one ds_write_b64 per tile (wave-private)
#pragma unroll
        for (int nt = 0; nt < 13; nt++) {
            bf p4[4];
#pragma unroll
            for (int r = 0; r < 4; r++) p4[r] = (bf)(sc[nt][r] * inv);
            *(uint2*)(P + l16 * SPS + nt * 16 + quad * 4) = *(uint2*)p4;
        }

        // out = P @ V : A-frag m=i=l16, k=j contiguous (7 ds_read_b128)
        v4f o[4];
#pragma unroll
        for (int n2 = 0; n2 < 4; n2++) o[n2] = (v4f){0.f, 0.f, 0.f, 0.f};
#pragma unroll
        for (int ks = 0; ks < 7; ks++) {
            v8bf aP;
            if (ks < 6 || quad < 2) {
                aP = *(const v8bf*)(P + l16 * SPS + ks * 32 + quad * 8);
            } else {
                // ks=6, quads 2,3: j=208..223 — P is zero there by construction
                uint4 z = make_uint4(0, 0, 0, 0);
                aP = *(v8bf*)&z;
            }
            int koff = ks * 32 + quad * 8;
            if (ks == 6 && quad >= 2) koff = 0;    // aP zero; keep bV read in-bounds/finite
#pragma unroll
            for (int n2 = 0; n2 < 4; n2++) {
                v8bf bV = *(const v8bf*)(sV + (n2 * 16 + l16) * SVS + koff);
                o[n2] = __builtin_amdgcn_mfma_f32_16x16x32_bf16(aP, bV, o[n2], 0, 0, 0);
            }
        }
        // store: row s = s0+quad*4+r, col d = n2*16+l16 (256B contiguous per row)
#pragma unroll
        for (int r = 0; r < 4; r++) {
            int s = s0 + quad * 4 + r;
            if (s < SEQ) {
#pragma unroll
                for (int n2 = 0; n2 < 4; n2++) {
                    int d = n2 * 16 + l16;
                    out[((size_t)b * SEQ + s) * HID + h * 64 + d] = o[n2][r];
                }
            }
        }
    }
}

// ---------------- launcher (round-3-proven workspace map) -------------------
extern "C" void kernel_launch(void* const* d_in, const int* in_sizes, int n_in,
                              void* d_out, int out_size, void* d_ws, size_t ws_size,
                              hipStream_t stream) {
    const float* X   = (const float*)d_in[0];
    const float* wq  = (const float*)d_in[1];
    const float* bq  = (const float*)d_in[2];
    const float* wk  = (const float*)d_in[3];
    const float* wv  = (const float*)d_in[4];
    const float* bv  = (const float*)d_in[5];
    const float* tbl = (const float*)d_in[6];
    float* out = (float*)d_out;

    char* ws = (char*)d_ws;
    bf*    Xb   = (bf*)ws;                          // 12608*768*2  = 19,365,888 B
    bf*    Wt   = (bf*)(ws + 19365888);             // 2304*768*2   =  3,538,944 B
    bf*    C    = (bf*)(ws + 22904832);             // 12608*2304*2 = 58,097,664 B
    float* bias = (float*)(ws + 81002496);          // 12*208*208*4 =  2,076,672 B

    kprep<<<11916, 256, 0, stream>>>(X, wq, wk, wv, tbl, Xb, Wt, bias);
    dim3 g(99, 18);
    kgemm<<<g, 256, 0, stream>>>(Xb, Wt, bq, bv, C);
    kattn<<<768, 256, 0, stream>>>(C, bias, out);
}